// Round 9
// baseline (118.023 us; speedup 1.0000x reference)
//
#include <hip/hip_runtime.h>
#include <hip/hip_bf16.h>
#include <math.h>

#define D 1024
#define NWG 256
#define N_STEPS 12
#define DELTA 2             // max allowed staleness (iterations)
#define PITCH 1032          // shorts per bW row: 1024 + 8 pad
#define LDS_BYTES (32 * PITCH * 2 + 1024 * 4 + 1024 * 4)   // bW + red + cld = 74240
#define ZELEMS (256 * 1024)  // shorts per z buffer (256 rows x 1024 cols)

typedef __attribute__((ext_vector_type(8))) short short8;
typedef __attribute__((ext_vector_type(4))) float f32x4;

__device__ __forceinline__ unsigned short f32_to_bf16_rne(float f) {
    union { float f; unsigned int u; } v; v.f = f;
    unsigned int u = v.u;
    u += 0x7FFFu + ((u >> 16) & 1u);
    return (unsigned short)(u >> 16);
}

// tanh via fast exp/rcp: rel err ~1e-6, far below the bf16 z floor
__device__ __forceinline__ float tanh_fast(float v) {
    v = fminf(15.f, fmaxf(-15.f, v));
    const float ex = __expf(2.f * v);
    return (ex - 1.f) * __builtin_amdgcn_rcpf(ex + 1.f);
}

// ---- LLC publication path (sc0 sc1): producer stores + flags.
// Consumer z reads are PLAIN cacheable loads: buffers are write-once and
// every read is flag-gated, so first touch always fetches a fresh LLC line.
__device__ __forceinline__ void llc_store8(short* p, unsigned long long v) {
    asm volatile("global_store_dwordx2 %0, %1, off sc0 sc1"
                 :: "v"(p), "v"(v) : "memory");
}
__device__ __forceinline__ void llc_store4(unsigned* p, unsigned v) {
    asm volatile("global_store_dword %0, %1, off sc0 sc1"
                 :: "v"(p), "v"(v) : "memory");
}
__device__ __forceinline__ unsigned llc_load4(const unsigned* p) {
    unsigned r;
    asm volatile("global_load_dword %0, %1, off sc0 sc1\n\t"
                 "s_waitcnt vmcnt(0)"
                 : "=v"(r) : "v"(p) : "memory");
    return r;
}
__device__ __forceinline__ void vmcnt0() {
    asm volatile("s_waitcnt vmcnt(0)" ::: "memory");
}

// Transpose W (f32 [k][j]) -> Wt (bf16 [j][k]); zero the 256 progress flags.
__global__ __launch_bounds__(256) void prep_wt(const float* __restrict__ W,
                                               short* __restrict__ Wt,
                                               unsigned* __restrict__ cnt) {
    __shared__ float tile[32][33];
    const int j0 = blockIdx.x * 32;
    const int k0 = blockIdx.y * 32;
    const int tx = threadIdx.x;   // 0..31
    const int ty = threadIdx.y;   // 0..7
    if (blockIdx.x == 0 && blockIdx.y == 0)
        cnt[ty * 32 + tx] = 0u;
    #pragma unroll
    for (int i = 0; i < 32; i += 8)
        tile[ty + i][tx] = W[(k0 + ty + i) * D + (j0 + tx)];
    __syncthreads();
    #pragma unroll
    for (int i = 0; i < 32; i += 8)
        Wt[(j0 + ty + i) * D + (k0 + tx)] = (short)f32_to_bf16_rne(tile[tx][ty + i]);
}

// 256 WGs: rg = bid>>5 owns rows [rg*32,+32); cg = bid&31 owns cols
// [cg*32,+32). Bounded-staleness async iteration: each WG free-runs, reading
// each producer's LATEST completed buffer (staleness <= DELTA, else poll).
// flag[p] = number of completed buffers by producer p (monotone). The
// minimum-progress WG never stalls -> deadlock-free; kernel time ~= slowest
// WG's own loop, not a 32-producer straggler chain per iteration.
__global__ __launch_bounds__(256, 2) void deq_solve(
    const float* __restrict__ b, const float* __restrict__ inj,
    const short* __restrict__ Wt, short* __restrict__ zbase,
    unsigned* __restrict__ cnt, float* __restrict__ out)
{
    extern __shared__ char smem[];
    short* bW  = (short*)smem;                       // [32 cols][PITCH] bf16
    float* red = (float*)(smem + 32 * PITCH * 2);    // [1024] split-K accumulator
    float* cld = red + 1024;                         // [1024] c tile f32

    const int tid  = threadIdx.x;
    const int lane = tid & 63;
    const int w    = tid >> 6;                       // wave id 0..3 (K-split)
    const int bid  = blockIdx.x;
    const int rg   = bid >> 5;
    const int cg   = bid & 31;
    const int c0   = cg * 32;
    const int r0   = rg * 32;
    unsigned* myflag = &cnt[rg * 32 + cg];

    // ---- init: Wt col-slice -> LDS; c tile; red zero ----
    for (int e = tid * 8; e < 32 * 1024; e += 256 * 8) {
        const int col = e >> 10, k = e & (D - 1);
        *(short8*)&bW[col * PITCH + k] = *(const short8*)&Wt[((c0 + col) << 10) + k];
    }
    #pragma unroll
    for (int s = 0; s < 4; ++s) {
        const int e = tid + s * 256;
        const int r = e >> 5, cc = e & 31;
        cld[e] = inj[(r0 + r) * D + c0 + cc] + b[c0 + cc];
        red[e] = 0.f;
    }
    __syncthreads();

    // z0 = tanh(c) (buffer 0), publish, flag = 1. No waiting — the staleness
    // window absorbs init skew.
    {
        const int e4 = tid * 4;
        const int gi = (r0 + (e4 >> 5)) * D + c0 + (e4 & 31);
        unsigned long long v = 0;
        #pragma unroll
        for (int j = 0; j < 4; ++j)
            v |= (unsigned long long)f32_to_bf16_rne(tanh_fast(cld[e4 + j])) << (16 * j);
        llc_store8(&zbase[gi], v);
    }
    vmcnt0();
    __syncthreads();
    if (tid == 0) llc_store4(myflag, 1u);

    const int lrow = lane & 15;
    const int lk   = (lane >> 4) * 8;
    const int rl   = (lane >> 4) * 4;
    const int cl   = lane & 15;
    const int base_off = (r0 + lrow) * D + w * 256 + lk;

    for (int t = 0; t < N_STEPS; ++t) {
        // ---- staleness window: flag[p] >= max(1, t-DELTA+1) for all 32
        // producers of my row group. Lane l (<32) polls producer l. ----
        const unsigned need = (t >= DELTA) ? (unsigned)(t - DELTA + 1) : 1u;
        unsigned fl = 0xFFFFFFFFu;
        if (lane < 32) fl = llc_load4(&cnt[rg * 32 + lane]);
        while (!__all((int)(fl >= need))) {
            __builtin_amdgcn_s_sleep(1);
            if (lane < 32) fl = llc_load4(&cnt[rg * 32 + lane]);
        }

        // ---- A fragments: fragment s of wave w <-> producer p = w*8+s.
        // Read p's latest completed buffer, clamped to t. Plain cacheable
        // loads (write-once + flag-gated => fresh; L2-shared within XCD). ----
        short8 a0[8], a1[8];
        #pragma unroll
        for (int s = 0; s < 8; ++s) {
            int flp  = __shfl((int)fl, w * 8 + s);
            int bidx = flp - 1; if (bidx > t) bidx = t;
            const short* ap = zbase + (size_t)bidx * ZELEMS + base_off + s * 32;
            a0[s] = *(const short8*)ap;
            a1[s] = *(const short8*)(ap + 16 * D);
        }

        const short* bp = &bW[lrow * PITCH + w * 256 + lk];
        f32x4 acc00 = {0.f,0.f,0.f,0.f}, acc01 = {0.f,0.f,0.f,0.f};
        f32x4 acc10 = {0.f,0.f,0.f,0.f}, acc11 = {0.f,0.f,0.f,0.f};
        #pragma unroll
        for (int s = 0; s < 8; ++s) {
            const short8 b0 = *(const short8*)(bp + s * 32);
            const short8 b1 = *(const short8*)(bp + 16 * PITCH + s * 32);
            acc00 = __builtin_amdgcn_mfma_f32_16x16x32_bf16(a0[s], b0, acc00, 0, 0, 0);
            acc01 = __builtin_amdgcn_mfma_f32_16x16x32_bf16(a0[s], b1, acc01, 0, 0, 0);
            acc10 = __builtin_amdgcn_mfma_f32_16x16x32_bf16(a1[s], b0, acc10, 0, 0, 0);
            acc11 = __builtin_amdgcn_mfma_f32_16x16x32_bf16(a1[s], b1, acc11, 0, 0, 0);
        }

        // split-K reduce into LDS
        #pragma unroll
        for (int q = 0; q < 4; ++q) {
            atomicAdd(&red[(rl + q) * 32 + cl],           acc00[q]);
            atomicAdd(&red[(rl + q) * 32 + cl + 16],      acc01[q]);
            atomicAdd(&red[(rl + 16 + q) * 32 + cl],      acc10[q]);
            atomicAdd(&red[(rl + 16 + q) * 32 + cl + 16], acc11[q]);
        }
        __syncthreads();

        // epilogue: 4 consecutive elements per thread
        const int e4 = tid * 4;
        const int gi = (r0 + (e4 >> 5)) * D + c0 + (e4 & 31);

        if (t == N_STEPS - 1) {
            f32x4 o;
            #pragma unroll
            for (int j = 0; j < 4; ++j)
                o[j] = tanh_fast(red[e4 + j] + cld[e4 + j]);
            *(f32x4*)(&out[gi]) = o;
        } else {
            unsigned long long v = 0;
            #pragma unroll
            for (int j = 0; j < 4; ++j) {
                const float val = tanh_fast(red[e4 + j] + cld[e4 + j]);
                red[e4 + j] = 0.f;   // re-zero for next iteration
                v |= (unsigned long long)f32_to_bf16_rne(val) << (16 * j);
            }
            llc_store8(zbase + (size_t)(t + 1) * ZELEMS + gi, v);  // publish
            vmcnt0();                // own stores at LLC before flagging
            __syncthreads();         // all waves drained; red re-zero visible
            if (tid == 0) llc_store4(myflag, (unsigned)(t + 2));
        }
    }
}

extern "C" void kernel_launch(void* const* d_in, const int* in_sizes, int n_in,
                              void* d_out, int out_size, void* d_ws, size_t ws_size,
                              hipStream_t stream) {
    const float* W   = (const float*)d_in[1];
    const float* b   = (const float*)d_in[2];
    const float* inj = (const float*)d_in[3];
    float* out = (float*)d_out;

    char* ws = (char*)d_ws;
    short* Wt    = (short*)ws;                          // 2 MB bf16 W^T
    short* zbase = (short*)(ws + 2 * 1024 * 1024);      // 12 x 512 KB write-once z
    unsigned* cnt = (unsigned*)(ws + 8 * 1024 * 1024);  // 256 u32 progress flags

    prep_wt<<<dim3(32, 32), dim3(32, 8), 0, stream>>>(W, Wt, cnt);
    deq_solve<<<dim3(NWG), dim3(256), LDS_BYTES, stream>>>(b, inj, Wt, zbase, cnt, out);
}